// Round 1
// baseline (1564.728 us; speedup 1.0000x reference)
//
#include <hip/hip_runtime.h>

#define DFEAT 256
#define NEG_ATT 0.2f
#define NEG_ACT 0.01f
#define BN_EPS 1e-5f

__device__ __forceinline__ float lrelu(float x, float s) { return x > 0.f ? x : s * x; }

// ---------------- histogram of dst ----------------
__global__ __launch_bounds__(256)
void hist_k(const int* __restrict__ dst, int E, int* __restrict__ counts) {
    int e = blockIdx.x * 256 + threadIdx.x;
    if (e < E) atomicAdd(&counts[dst[e]], 1);
}

// ---------------- hierarchical exclusive scan (3 kernels) ----------------
__global__ __launch_bounds__(256)
void scan1_k(const int* __restrict__ counts, int* __restrict__ offs,
             int* __restrict__ bsums, int N) {
    __shared__ int buf[256];
    int t = threadIdx.x;
    int i = blockIdx.x * 256 + t;
    int v = (i < N) ? counts[i] : 0;
    buf[t] = v;
    __syncthreads();
    for (int off = 1; off < 256; off <<= 1) {
        int x = (t >= off) ? buf[t - off] : 0;
        __syncthreads();
        buf[t] += x;
        __syncthreads();
    }
    if (i < N) offs[i] = buf[t];            // inclusive within block
    if (t == 255) bsums[blockIdx.x] = buf[255];
}

__global__ __launch_bounds__(256)
void scan2_k(int* __restrict__ bsums, int nb) {   // exclusive scan in place, single block
    __shared__ int buf[256];
    __shared__ int carry_s;
    int t = threadIdx.x;
    if (t == 0) carry_s = 0;
    __syncthreads();
    for (int base = 0; base < nb; base += 256) {
        int i = base + t;
        int v = (i < nb) ? bsums[i] : 0;
        buf[t] = v;
        __syncthreads();
        for (int off = 1; off < 256; off <<= 1) {
            int x = (t >= off) ? buf[t - off] : 0;
            __syncthreads();
            buf[t] += x;
            __syncthreads();
        }
        int incl = buf[t];
        int c = carry_s;
        if (i < nb) bsums[i] = c + incl - v;
        __syncthreads();
        if (t == 255) carry_s = c + buf[255];
        __syncthreads();
    }
}

__global__ __launch_bounds__(256)
void scan3_k(int* __restrict__ offs, const int* __restrict__ counts,
             const int* __restrict__ bsums, int N, int E) {
    int i = blockIdx.x * 256 + threadIdx.x;
    if (i < N) offs[i] = offs[i] - counts[i] + bsums[blockIdx.x];
    if (i == 0) offs[N] = E;
}

// ---------------- scatter edges into CSR ----------------
__global__ __launch_bounds__(256)
void scatter_k(const int* __restrict__ src, const int* __restrict__ dst, int E,
               const int* __restrict__ offs, int* __restrict__ cursor,
               int* __restrict__ csr) {
    int e = blockIdx.x * 256 + threadIdx.x;
    if (e >= E) return;
    int d = dst[e];
    int pos = atomicAdd(&cursor[d], 1);
    csr[offs[d] + pos] = src[e];
}

// ---------------- GEMM: C[M,256] = A[M,K] @ B[K,256], K % 16 == 0 ----------------
__global__ __launch_bounds__(256)
void gemm_k(const float* __restrict__ A, const float* __restrict__ B,
            float* __restrict__ C, int M, int K) {
    const int BK = 16;
    __shared__ float As[BK][64 + 4];
    __shared__ float Bs[BK][64];
    int tid = threadIdx.x;
    int bm = blockIdx.x * 64;
    int bn = blockIdx.y * 64;
    int tx = tid & 15, ty = tid >> 4;
    float acc[4][4] = {{0.f}};
    for (int k0 = 0; k0 < K; k0 += BK) {
        int row = tid >> 2;
        int kq = (tid & 3) << 2;
        int gr = bm + row;
        float4 a = make_float4(0.f, 0.f, 0.f, 0.f);
        if (gr < M) a = *(const float4*)(A + (size_t)gr * K + k0 + kq);
        As[kq + 0][row] = a.x; As[kq + 1][row] = a.y;
        As[kq + 2][row] = a.z; As[kq + 3][row] = a.w;
        int kr = tid >> 4;
        int c4 = (tid & 15) << 2;
        *(float4*)&Bs[kr][c4] = *(const float4*)(B + (size_t)(k0 + kr) * DFEAT + bn + c4);
        __syncthreads();
#pragma unroll
        for (int k = 0; k < BK; ++k) {
            float a0 = As[k][ty * 4 + 0], a1 = As[k][ty * 4 + 1];
            float a2 = As[k][ty * 4 + 2], a3 = As[k][ty * 4 + 3];
            float b0 = Bs[k][tx * 4 + 0], b1 = Bs[k][tx * 4 + 1];
            float b2 = Bs[k][tx * 4 + 2], b3 = Bs[k][tx * 4 + 3];
            acc[0][0] += a0 * b0; acc[0][1] += a0 * b1; acc[0][2] += a0 * b2; acc[0][3] += a0 * b3;
            acc[1][0] += a1 * b0; acc[1][1] += a1 * b1; acc[1][2] += a1 * b2; acc[1][3] += a1 * b3;
            acc[2][0] += a2 * b0; acc[2][1] += a2 * b1; acc[2][2] += a2 * b2; acc[2][3] += a2 * b3;
            acc[3][0] += a3 * b0; acc[3][1] += a3 * b1; acc[3][2] += a3 * b2; acc[3][3] += a3 * b3;
        }
        __syncthreads();
    }
    for (int i2 = 0; i2 < 4; ++i2) {
        int gr = bm + ty * 4 + i2;
        if (gr < M) {
            float4 o = make_float4(acc[i2][0], acc[i2][1], acc[i2][2], acc[i2][3]);
            *(float4*)(C + (size_t)gr * DFEAT + bn + tx * 4) = o;
        }
    }
}

// ---------------- GATv2 gather: one wave per dst node, online softmax ----------------
__global__ __launch_bounds__(256)
void gat_gather_k(const float* __restrict__ hl, const float* __restrict__ hr,
                  const int* __restrict__ offs, const int* __restrict__ csr,
                  const float* __restrict__ att, const float* __restrict__ bias,
                  float* __restrict__ out, int N) {
    int wave = (blockIdx.x * 256 + threadIdx.x) >> 6;
    int lane = threadIdx.x & 63;
    if (wave >= N) return;
    int d = wave;
    int f4 = lane << 2;                 // features f4..f4+3, head = lane>>4
    float4 hrv = *(const float4*)(hr + (size_t)d * DFEAT + f4);
    float4 av  = *(const float4*)(att + f4);
    float4 bv  = *(const float4*)(bias + f4);
    float m = -INFINITY, l = 0.f;
    float ac0 = 0.f, ac1 = 0.f, ac2 = 0.f, ac3 = 0.f;
    int beg = offs[d], end = offs[d + 1];
    for (int e = beg - 1; e < end; ++e) {
        int s = (e < beg) ? d : csr[e];           // self-loop first
        float4 hlv = *(const float4*)(hl + (size_t)s * DFEAT + f4);
        float e0 = lrelu(hlv.x + hrv.x, NEG_ATT);
        float e1 = lrelu(hlv.y + hrv.y, NEG_ATT);
        float e2 = lrelu(hlv.z + hrv.z, NEG_ATT);
        float e3 = lrelu(hlv.w + hrv.w, NEG_ATT);
        float part = e0 * av.x + e1 * av.y + e2 * av.z + e3 * av.w;
        part += __shfl_xor(part, 1, 16);
        part += __shfl_xor(part, 2, 16);
        part += __shfl_xor(part, 4, 16);
        part += __shfl_xor(part, 8, 16);
        float sc = part;                 // per-head score, uniform across the 16 lanes
        float m_new = fmaxf(m, sc);
        float p   = __expf(sc - m_new);
        float fac = __expf(m - m_new);   // m=-inf initially -> fac=0
        l = l * fac + p;
        ac0 = ac0 * fac + p * hlv.x;
        ac1 = ac1 * fac + p * hlv.y;
        ac2 = ac2 * fac + p * hlv.z;
        ac3 = ac3 * fac + p * hlv.w;
        m = m_new;
    }
    float inv = 1.f / (l + 1e-16f);
    float4 o;
    o.x = ac0 * inv + bv.x;
    o.y = ac1 * inv + bv.y;
    o.z = ac2 * inv + bv.z;
    o.w = ac3 * inv + bv.w;
    *(float4*)(out + (size_t)d * DFEAT + f4) = o;
}

// ---------------- BatchNorm stats: column sums / sumsq ----------------
__global__ __launch_bounds__(256)
void bn_stats_k(const float* __restrict__ h, float* __restrict__ stats, int N) {
    int f = threadIdx.x;                      // 0..255
    float s = 0.f, s2 = 0.f;
    for (int r = blockIdx.x; r < N; r += gridDim.x) {
        float v = h[(size_t)r * DFEAT + f];
        s += v; s2 += v * v;
    }
    atomicAdd(&stats[f], s);
    atomicAdd(&stats[DFEAT + f], s2);
}

// ---------------- BatchNorm apply + leaky_relu(0.01) ----------------
__global__ __launch_bounds__(256)
void bn_apply_k(const float* __restrict__ in, float* __restrict__ outp,
                const float* __restrict__ stats, const float* __restrict__ g,
                const float* __restrict__ b, int N) {
    size_t idx = (size_t)blockIdx.x * 256 + threadIdx.x;   // float4 index
    if (idx >= (size_t)N * 64) return;
    int f4 = ((int)(idx & 63)) << 2;
    float invN = 1.f / (float)N;
    float4 v = ((const float4*)in)[idx];
    float o[4], vv[4] = {v.x, v.y, v.z, v.w};
#pragma unroll
    for (int j = 0; j < 4; ++j) {
        int f = f4 + j;
        float mu  = stats[f] * invN;
        float var = stats[DFEAT + f] * invN - mu * mu;
        float sc  = g[f] / sqrtf(var + BN_EPS);
        float val = (vv[j] - mu) * sc + b[f];
        o[j] = lrelu(val, NEG_ACT);
    }
    float4 ov = make_float4(o[0], o[1], o[2], o[3]);
    ((float4*)outp)[idx] = ov;
}

// ---------------- classifier: out[N,2] = h @ cW + cb, one wave per node ----------------
__global__ __launch_bounds__(256)
void classifier_k(const float* __restrict__ h, const float* __restrict__ cW,
                  const float* __restrict__ cb, float* __restrict__ out, int N) {
    int wave = (blockIdx.x * 256 + threadIdx.x) >> 6;
    int lane = threadIdx.x & 63;
    if (wave >= N) return;
    int f4 = lane << 2;
    float4 v = *(const float4*)(h + (size_t)wave * DFEAT + f4);
    float p0 = v.x * cW[(f4 + 0) * 2] + v.y * cW[(f4 + 1) * 2]
             + v.z * cW[(f4 + 2) * 2] + v.w * cW[(f4 + 3) * 2];
    float p1 = v.x * cW[(f4 + 0) * 2 + 1] + v.y * cW[(f4 + 1) * 2 + 1]
             + v.z * cW[(f4 + 2) * 2 + 1] + v.w * cW[(f4 + 3) * 2 + 1];
#pragma unroll
    for (int off = 1; off < 64; off <<= 1) {
        p0 += __shfl_xor(p0, off);
        p1 += __shfl_xor(p1, off);
    }
    if (lane == 0) {
        out[(size_t)wave * 2 + 0] = p0 + cb[0];
        out[(size_t)wave * 2 + 1] = p1 + cb[1];
    }
}

extern "C" void kernel_launch(void* const* d_in, const int* in_sizes, int n_in,
                              void* d_out, int out_size, void* d_ws, size_t ws_size,
                              hipStream_t stream) {
    const float* x[3]  = {(const float*)d_in[0], (const float*)d_in[1], (const float*)d_in[2]};
    const int*   ei[3] = {(const int*)d_in[3], (const int*)d_in[4], (const int*)d_in[5]};
    const float* Wl1 = (const float*)d_in[6];
    const float* Wr1 = (const float*)d_in[7];
    const float* att1 = (const float*)d_in[8];
    const float* b1 = (const float*)d_in[9];
    const float* Wl2 = (const float*)d_in[10];
    const float* Wr2 = (const float*)d_in[11];
    const float* att2 = (const float*)d_in[12];
    const float* b2 = (const float*)d_in[13];
    const float* bn_g = (const float*)d_in[14];
    const float* bn_b = (const float*)d_in[15];
    const float* cW = (const float*)d_in[16];
    const float* cb = (const float*)d_in[17];

    int Ns[3] = {in_sizes[0] / 128, in_sizes[1] / 128, in_sizes[2] / 128};
    int Es[3] = {in_sizes[3] / 2, in_sizes[4] / 2, in_sizes[5] / 2};
    int maxN = Ns[0], maxE = Es[0];
    for (int i = 1; i < 3; ++i) {
        if (Ns[i] > maxN) maxN = Ns[i];
        if (Es[i] > maxE) maxE = Es[i];
    }

    // workspace layout (deterministic each call)
    char* w = (char*)d_ws;
    auto alloc_b = [&](size_t bytes) -> void* {
        void* p = (void*)w;
        w += (bytes + 255) & ~(size_t)255;
        return p;
    };
    float* P = (float*)alloc_b((size_t)maxN * DFEAT * sizeof(float));
    float* Q = (float*)alloc_b((size_t)maxN * DFEAT * sizeof(float));
    float* R = (float*)alloc_b((size_t)maxN * DFEAT * sizeof(float));
    int* counts = (int*)alloc_b((size_t)maxN * sizeof(int));
    int* offs   = (int*)alloc_b((size_t)(maxN + 1) * sizeof(int));
    int* csr    = (int*)alloc_b((size_t)maxE * sizeof(int));
    int* bsums  = (int*)alloc_b(((size_t)(maxN + 255) / 256) * sizeof(int));
    float* stats = (float*)alloc_b(2 * DFEAT * sizeof(float));

    float* out = (float*)d_out;
    size_t out_off = 0;

    for (int i = 0; i < 3; ++i) {
        int N = Ns[i], E = Es[i];
        const int* src = ei[i];
        const int* dst = ei[i] + E;
        int nblkN = (N + 255) / 256;
        int nblkE = (E + 255) / 256;
        int nwave = (N + 3) / 4;

        // ---- CSR build (reused by both layers) ----
        hipMemsetAsync(counts, 0, (size_t)N * sizeof(int), stream);
        hist_k<<<nblkE, 256, 0, stream>>>(dst, E, counts);
        scan1_k<<<nblkN, 256, 0, stream>>>(counts, offs, bsums, N);
        scan2_k<<<1, 256, 0, stream>>>(bsums, nblkN);
        scan3_k<<<nblkN, 256, 0, stream>>>(offs, counts, bsums, N, E);
        hipMemsetAsync(counts, 0, (size_t)N * sizeof(int), stream);
        scatter_k<<<nblkE, 256, 0, stream>>>(src, dst, E, offs, counts, csr);

        dim3 gg((N + 63) / 64, DFEAT / 64);

        // ---- layer 1 ----
        gemm_k<<<gg, 256, 0, stream>>>(x[i], Wl1 + (size_t)i * 128 * DFEAT, P, N, 128);
        gemm_k<<<gg, 256, 0, stream>>>(x[i], Wr1 + (size_t)i * 128 * DFEAT, Q, N, 128);
        gat_gather_k<<<nwave, 256, 0, stream>>>(P, Q, offs, csr,
                                                att1 + (size_t)i * DFEAT,
                                                b1 + (size_t)i * DFEAT, R, N);
        hipMemsetAsync(stats, 0, 2 * DFEAT * sizeof(float), stream);
        bn_stats_k<<<256, 256, 0, stream>>>(R, stats, N);
        bn_apply_k<<<(N * 64 + 255) / 256, 256, 0, stream>>>(
            R, Q, stats, bn_g + (size_t)i * DFEAT, bn_b + (size_t)i * DFEAT, N);

        // ---- layer 2 ----
        gemm_k<<<gg, 256, 0, stream>>>(Q, Wl2 + (size_t)i * DFEAT * DFEAT, P, N, DFEAT);
        gemm_k<<<gg, 256, 0, stream>>>(Q, Wr2 + (size_t)i * DFEAT * DFEAT, R, N, DFEAT);
        gat_gather_k<<<nwave, 256, 0, stream>>>(P, R, offs, csr,
                                                att2 + (size_t)i * DFEAT,
                                                b2 + (size_t)i * DFEAT, Q, N);
        hipMemsetAsync(stats, 0, 2 * DFEAT * sizeof(float), stream);
        bn_stats_k<<<256, 256, 0, stream>>>(Q, stats, N);
        bn_apply_k<<<(N * 64 + 255) / 256, 256, 0, stream>>>(
            Q, P, stats, bn_g + (size_t)i * DFEAT, bn_b + (size_t)i * DFEAT, N);

        // ---- classifier ----
        classifier_k<<<nwave, 256, 0, stream>>>(P, cW, cb, out + out_off, N);
        out_off += (size_t)N * 2;
    }
}

// Round 2
// 1007.279 us; speedup vs baseline: 1.5534x; 1.5534x over previous
//
#include <hip/hip_runtime.h>

#define DFEAT 256
#define NEG_ATT 0.2f
#define NEG_ACT 0.01f
#define BN_EPS 1e-5f

typedef short bf16x8 __attribute__((ext_vector_type(8)));
typedef float f32x4 __attribute__((ext_vector_type(4)));

__device__ __forceinline__ float lrelu(float x, float s) { return x > 0.f ? x : s * x; }

__device__ __forceinline__ unsigned short f2bf(float f) {
    union { float f; unsigned int u; } v; v.f = f;
    unsigned int u = v.u;
    unsigned int r = (u + 0x7FFFu + ((u >> 16) & 1u)) >> 16;   // RNE
    return (unsigned short)r;
}
__device__ __forceinline__ float bf2f(unsigned short s) {
    union { unsigned int u; float f; } v; v.u = ((unsigned int)s) << 16;
    return v.f;
}

// ---------------- histogram of dst ----------------
__global__ __launch_bounds__(256)
void hist_k(const int* __restrict__ dst, int E, int* __restrict__ counts) {
    int e = blockIdx.x * 256 + threadIdx.x;
    if (e < E) atomicAdd(&counts[dst[e]], 1);
}

// ---------------- hierarchical exclusive scan (3 kernels) ----------------
__global__ __launch_bounds__(256)
void scan1_k(const int* __restrict__ counts, int* __restrict__ offs,
             int* __restrict__ bsums, int N) {
    __shared__ int buf[256];
    int t = threadIdx.x;
    int i = blockIdx.x * 256 + t;
    int v = (i < N) ? counts[i] : 0;
    buf[t] = v;
    __syncthreads();
    for (int off = 1; off < 256; off <<= 1) {
        int x = (t >= off) ? buf[t - off] : 0;
        __syncthreads();
        buf[t] += x;
        __syncthreads();
    }
    if (i < N) offs[i] = buf[t];            // inclusive within block
    if (t == 255) bsums[blockIdx.x] = buf[255];
}

__global__ __launch_bounds__(256)
void scan2_k(int* __restrict__ bsums, int nb) {   // exclusive scan in place
    __shared__ int buf[256];
    __shared__ int carry_s;
    int t = threadIdx.x;
    if (t == 0) carry_s = 0;
    __syncthreads();
    for (int base = 0; base < nb; base += 256) {
        int i = base + t;
        int v = (i < nb) ? bsums[i] : 0;
        buf[t] = v;
        __syncthreads();
        for (int off = 1; off < 256; off <<= 1) {
            int x = (t >= off) ? buf[t - off] : 0;
            __syncthreads();
            buf[t] += x;
            __syncthreads();
        }
        int incl = buf[t];
        int c = carry_s;
        if (i < nb) bsums[i] = c + incl - v;
        __syncthreads();
        if (t == 255) carry_s = c + buf[255];
        __syncthreads();
    }
}

__global__ __launch_bounds__(256)
void scan3_k(int* __restrict__ offs, const int* __restrict__ counts,
             const int* __restrict__ bsums, int N, int E) {
    int i = blockIdx.x * 256 + threadIdx.x;
    if (i < N) offs[i] = offs[i] - counts[i] + bsums[blockIdx.x];
    if (i == 0) offs[N] = E;
}

// ---------------- scatter edges into CSR ----------------
__global__ __launch_bounds__(256)
void scatter_k(const int* __restrict__ src, const int* __restrict__ dst, int E,
               const int* __restrict__ offs, int* __restrict__ cursor,
               int* __restrict__ csr) {
    int e = blockIdx.x * 256 + threadIdx.x;
    if (e >= E) return;
    int d = dst[e];
    int pos = atomicAdd(&cursor[d], 1);
    csr[offs[d] + pos] = src[e];
}

// ---------------- fp32 -> bf16 cast (vectorized) ----------------
__global__ __launch_bounds__(256)
void cast_k(const float* __restrict__ in, unsigned short* __restrict__ out, long n4) {
    long i = (long)blockIdx.x * 256 + threadIdx.x;   // float4 groups
    if (i >= n4) return;
    float4 v = ((const float4*)in)[i];
    ushort4 o;
    o.x = f2bf(v.x); o.y = f2bf(v.y); o.z = f2bf(v.z); o.w = f2bf(v.w);
    ((ushort4*)out)[i] = o;
}

// ---------------- weight cast+transpose: Bt[512][K] = concat(Wl,Wr)^T ----------------
__global__ __launch_bounds__(256)
void wcast_k(const float* __restrict__ Wl, const float* __restrict__ Wr,
             unsigned short* __restrict__ Bt, int K) {
    int idx = blockIdx.x * 256 + threadIdx.x;
    if (idx >= 512 * K) return;
    int n = idx / K, k = idx - n * K;
    const float* W = (n < 256) ? Wl : Wr;
    int nn = n & 255;
    Bt[idx] = f2bf(W[(size_t)k * 256 + nn]);
}

// ---------------- MFMA GEMM: C[M,512] bf16 = A[M,K] bf16 @ Bt[512,K]^T ----------------
__global__ __launch_bounds__(256)
void mfma_gemm_k(const unsigned short* __restrict__ A, const unsigned short* __restrict__ Bt,
                 unsigned short* __restrict__ C, int M, int K) {
    const int LDK = 40;                       // padded LDS row stride (bank-friendly)
    __shared__ unsigned short As[128 * LDK];
    __shared__ unsigned short Bs[128 * LDK];
    int tid = threadIdx.x;
    int bm = blockIdx.x * 128;
    int bn = blockIdx.y * 128;
    int wid = tid >> 6, lane = tid & 63;
    int quad = lane >> 4, l16 = lane & 15;
    int mw = (wid & 1) * 64, nw = (wid >> 1) * 64;
    f32x4 acc[4][4] = {};
    for (int k0 = 0; k0 < K; k0 += 32) {
        // stage: 512 chunks of 16B per tile, 2 per thread per tile
#pragma unroll
        for (int i = 0; i < 2; ++i) {
            int c = tid + 256 * i;            // 0..511
            int row = c >> 2, ko = (c & 3) * 8;
            int ra = bm + row; if (ra >= M) ra = M - 1;
            uint4 va = *(const uint4*)(A + (size_t)ra * K + k0 + ko);
            *(uint4*)&As[row * LDK + ko] = va;
            uint4 vb = *(const uint4*)(Bt + (size_t)(bn + row) * K + k0 + ko);
            *(uint4*)&Bs[row * LDK + ko] = vb;
        }
        __syncthreads();
        bf16x8 af[4], bfv[4];
#pragma unroll
        for (int i = 0; i < 4; ++i)
            af[i] = *(bf16x8*)&As[(mw + 16 * i + l16) * LDK + quad * 8];
#pragma unroll
        for (int t = 0; t < 4; ++t)
            bfv[t] = *(bf16x8*)&Bs[(nw + 16 * t + l16) * LDK + quad * 8];
#pragma unroll
        for (int i = 0; i < 4; ++i)
#pragma unroll
            for (int t = 0; t < 4; ++t)
                acc[i][t] = __builtin_amdgcn_mfma_f32_16x16x32_bf16(af[i], bfv[t], acc[i][t], 0, 0, 0);
        __syncthreads();
    }
    // epilogue: row = bm+mw+16i+quad*4+r, col = bn+nw+16t+l16
#pragma unroll
    for (int i = 0; i < 4; ++i) {
#pragma unroll
        for (int r = 0; r < 4; ++r) {
            int grow = bm + mw + 16 * i + quad * 4 + r;
            if (grow < M) {
#pragma unroll
                for (int t = 0; t < 4; ++t) {
                    int gcol = bn + nw + 16 * t + l16;
                    C[(size_t)grow * 512 + gcol] = f2bf(acc[i][t][r]);
                }
            }
        }
    }
}

// ---------------- GATv2 gather (bf16 hl/hr, row stride 512), online softmax ----------------
__global__ __launch_bounds__(256)
void gat_gather_k(const unsigned short* __restrict__ hl, const unsigned short* __restrict__ hr,
                  const int* __restrict__ offs, const int* __restrict__ csr,
                  const float* __restrict__ att, const float* __restrict__ bias,
                  float* __restrict__ out, int N) {
    int wave = (blockIdx.x * 256 + threadIdx.x) >> 6;
    int lane = threadIdx.x & 63;
    if (wave >= N) return;
    int d = wave;
    int f4 = lane << 2;                 // features f4..f4+3, head = lane>>4
    ushort4 hru = *(const ushort4*)(hr + (size_t)d * 512 + f4);
    float hr0 = bf2f(hru.x), hr1 = bf2f(hru.y), hr2 = bf2f(hru.z), hr3 = bf2f(hru.w);
    float4 av  = *(const float4*)(att + f4);
    float4 bv  = *(const float4*)(bias + f4);
    float m = -INFINITY, l = 0.f;
    float ac0 = 0.f, ac1 = 0.f, ac2 = 0.f, ac3 = 0.f;
    int beg = offs[d], end = offs[d + 1];
    for (int e = beg - 1; e < end; ++e) {
        int s = (e < beg) ? d : csr[e];           // self-loop first
        ushort4 hlu = *(const ushort4*)(hl + (size_t)s * 512 + f4);
        float h0 = bf2f(hlu.x), h1 = bf2f(hlu.y), h2 = bf2f(hlu.z), h3 = bf2f(hlu.w);
        float e0 = lrelu(h0 + hr0, NEG_ATT);
        float e1 = lrelu(h1 + hr1, NEG_ATT);
        float e2 = lrelu(h2 + hr2, NEG_ATT);
        float e3 = lrelu(h3 + hr3, NEG_ATT);
        float part = e0 * av.x + e1 * av.y + e2 * av.z + e3 * av.w;
        part += __shfl_xor(part, 1, 16);
        part += __shfl_xor(part, 2, 16);
        part += __shfl_xor(part, 4, 16);
        part += __shfl_xor(part, 8, 16);
        float sc = part;                 // per-head score, uniform across the 16 lanes
        float m_new = fmaxf(m, sc);
        float p   = __expf(sc - m_new);
        float fac = __expf(m - m_new);   // m=-inf initially -> fac=0
        l = l * fac + p;
        ac0 = ac0 * fac + p * h0;
        ac1 = ac1 * fac + p * h1;
        ac2 = ac2 * fac + p * h2;
        ac3 = ac3 * fac + p * h3;
        m = m_new;
    }
    float inv = 1.f / (l + 1e-16f);
    float4 o;
    o.x = ac0 * inv + bv.x;
    o.y = ac1 * inv + bv.y;
    o.z = ac2 * inv + bv.z;
    o.w = ac3 * inv + bv.w;
    *(float4*)(out + (size_t)d * DFEAT + f4) = o;
}

// ---------------- BatchNorm stats: column sums / sumsq ----------------
__global__ __launch_bounds__(256)
void bn_stats_k(const float* __restrict__ h, float* __restrict__ stats, int N) {
    int f = threadIdx.x;                      // 0..255
    float s = 0.f, s2 = 0.f;
    for (int r = blockIdx.x; r < N; r += gridDim.x) {
        float v = h[(size_t)r * DFEAT + f];
        s += v; s2 += v * v;
    }
    atomicAdd(&stats[f], s);
    atomicAdd(&stats[DFEAT + f], s2);
}

// ---------------- BatchNorm apply + leaky_relu, fp32 out (in-place safe) ----------------
__global__ __launch_bounds__(256)
void bn_apply_f32_k(const float* __restrict__ in, float* __restrict__ outp,
                    const float* __restrict__ stats, const float* __restrict__ g,
                    const float* __restrict__ b, int N) {
    size_t idx = (size_t)blockIdx.x * 256 + threadIdx.x;   // float4 index
    if (idx >= (size_t)N * 64) return;
    int f4 = ((int)(idx & 63)) << 2;
    float invN = 1.f / (float)N;
    float4 v = ((const float4*)in)[idx];
    float o[4], vv[4] = {v.x, v.y, v.z, v.w};
#pragma unroll
    for (int j = 0; j < 4; ++j) {
        int f = f4 + j;
        float mu  = stats[f] * invN;
        float var = stats[DFEAT + f] * invN - mu * mu;
        float sc  = g[f] / sqrtf(var + BN_EPS);
        float val = (vv[j] - mu) * sc + b[f];
        o[j] = lrelu(val, NEG_ACT);
    }
    ((float4*)outp)[idx] = make_float4(o[0], o[1], o[2], o[3]);
}

// ---------------- BatchNorm apply + leaky_relu, bf16 out ----------------
__global__ __launch_bounds__(256)
void bn_apply_bf16_k(const float* __restrict__ in, unsigned short* __restrict__ outp,
                     const float* __restrict__ stats, const float* __restrict__ g,
                     const float* __restrict__ b, int N) {
    size_t idx = (size_t)blockIdx.x * 256 + threadIdx.x;   // float4 index
    if (idx >= (size_t)N * 64) return;
    int f4 = ((int)(idx & 63)) << 2;
    float invN = 1.f / (float)N;
    float4 v = ((const float4*)in)[idx];
    float o[4], vv[4] = {v.x, v.y, v.z, v.w};
#pragma unroll
    for (int j = 0; j < 4; ++j) {
        int f = f4 + j;
        float mu  = stats[f] * invN;
        float var = stats[DFEAT + f] * invN - mu * mu;
        float sc  = g[f] / sqrtf(var + BN_EPS);
        float val = (vv[j] - mu) * sc + b[f];
        o[j] = lrelu(val, NEG_ACT);
    }
    ushort4 ov;
    ov.x = f2bf(o[0]); ov.y = f2bf(o[1]); ov.z = f2bf(o[2]); ov.w = f2bf(o[3]);
    ((ushort4*)outp)[idx] = ov;
}

// ---------------- classifier: out[N,2] = h @ cW + cb, one wave per node ----------------
__global__ __launch_bounds__(256)
void classifier_k(const float* __restrict__ h, const float* __restrict__ cW,
                  const float* __restrict__ cb, float* __restrict__ out, int N) {
    int wave = (blockIdx.x * 256 + threadIdx.x) >> 6;
    int lane = threadIdx.x & 63;
    if (wave >= N) return;
    int f4 = lane << 2;
    float4 v = *(const float4*)(h + (size_t)wave * DFEAT + f4);
    float p0 = v.x * cW[(f4 + 0) * 2] + v.y * cW[(f4 + 1) * 2]
             + v.z * cW[(f4 + 2) * 2] + v.w * cW[(f4 + 3) * 2];
    float p1 = v.x * cW[(f4 + 0) * 2 + 1] + v.y * cW[(f4 + 1) * 2 + 1]
             + v.z * cW[(f4 + 2) * 2 + 1] + v.w * cW[(f4 + 3) * 2 + 1];
#pragma unroll
    for (int off = 1; off < 64; off <<= 1) {
        p0 += __shfl_xor(p0, off);
        p1 += __shfl_xor(p1, off);
    }
    if (lane == 0) {
        out[(size_t)wave * 2 + 0] = p0 + cb[0];
        out[(size_t)wave * 2 + 1] = p1 + cb[1];
    }
}

extern "C" void kernel_launch(void* const* d_in, const int* in_sizes, int n_in,
                              void* d_out, int out_size, void* d_ws, size_t ws_size,
                              hipStream_t stream) {
    const float* x[3]  = {(const float*)d_in[0], (const float*)d_in[1], (const float*)d_in[2]};
    const int*   ei[3] = {(const int*)d_in[3], (const int*)d_in[4], (const int*)d_in[5]};
    const float* Wl1 = (const float*)d_in[6];
    const float* Wr1 = (const float*)d_in[7];
    const float* att1 = (const float*)d_in[8];
    const float* b1 = (const float*)d_in[9];
    const float* Wl2 = (const float*)d_in[10];
    const float* Wr2 = (const float*)d_in[11];
    const float* att2 = (const float*)d_in[12];
    const float* b2 = (const float*)d_in[13];
    const float* bn_g = (const float*)d_in[14];
    const float* bn_b = (const float*)d_in[15];
    const float* cW = (const float*)d_in[16];
    const float* cb = (const float*)d_in[17];

    int Ns[3] = {in_sizes[0] / 128, in_sizes[1] / 128, in_sizes[2] / 128};
    int Es[3] = {in_sizes[3] / 2, in_sizes[4] / 2, in_sizes[5] / 2};
    int maxN = Ns[0], maxE = Es[0];
    for (int i = 1; i < 3; ++i) {
        if (Ns[i] > maxN) maxN = Ns[i];
        if (Es[i] > maxE) maxE = Es[i];
    }

    // workspace layout (deterministic each call)
    char* w = (char*)d_ws;
    auto alloc_b = [&](size_t bytes) -> void* {
        void* p = (void*)w;
        w += (bytes + 255) & ~(size_t)255;
        return p;
    };
    unsigned short* Xb = (unsigned short*)alloc_b((size_t)maxN * DFEAT * sizeof(unsigned short)); // A input (bf16), reused L1/L2
    unsigned short* C  = (unsigned short*)alloc_b((size_t)maxN * 512 * sizeof(unsigned short));   // GEMM out hl||hr (bf16)
    float* R = (float*)alloc_b((size_t)maxN * DFEAT * sizeof(float));                             // gather out / bn buffer
    unsigned short* Bt = (unsigned short*)alloc_b((size_t)512 * DFEAT * sizeof(unsigned short));  // weights ^T (bf16)
    int* counts = (int*)alloc_b((size_t)maxN * sizeof(int));
    int* offs   = (int*)alloc_b((size_t)(maxN + 1) * sizeof(int));
    int* csr    = (int*)alloc_b((size_t)maxE * sizeof(int));
    int* bsums  = (int*)alloc_b(((size_t)(maxN + 255) / 256) * sizeof(int));
    float* stats = (float*)alloc_b(2 * DFEAT * sizeof(float));

    float* out = (float*)d_out;
    size_t out_off = 0;

    for (int i = 0; i < 3; ++i) {
        int N = Ns[i], E = Es[i];
        const int* src = ei[i];
        const int* dst = ei[i] + E;
        int nblkN = (N + 255) / 256;
        int nblkE = (E + 255) / 256;
        int nwave = (N + 3) / 4;

        // ---- CSR build (reused by both layers) ----
        hipMemsetAsync(counts, 0, (size_t)N * sizeof(int), stream);
        hist_k<<<nblkE, 256, 0, stream>>>(dst, E, counts);
        scan1_k<<<nblkN, 256, 0, stream>>>(counts, offs, bsums, N);
        scan2_k<<<1, 256, 0, stream>>>(bsums, nblkN);
        scan3_k<<<nblkN, 256, 0, stream>>>(offs, counts, bsums, N, E);
        hipMemsetAsync(counts, 0, (size_t)N * sizeof(int), stream);
        scatter_k<<<nblkE, 256, 0, stream>>>(src, dst, E, offs, counts, csr);

        dim3 gg((N + 127) / 128, 4);

        // ---- layer 1 ----
        cast_k<<<(int)(((long)N * 128 / 4 + 255) / 256), 256, 0, stream>>>(x[i], Xb, (long)N * 128 / 4);
        wcast_k<<<(512 * 128 + 255) / 256, 256, 0, stream>>>(
            Wl1 + (size_t)i * 128 * DFEAT, Wr1 + (size_t)i * 128 * DFEAT, Bt, 128);
        mfma_gemm_k<<<gg, 256, 0, stream>>>(Xb, Bt, C, N, 128);
        gat_gather_k<<<nwave, 256, 0, stream>>>(C, C + 256, offs, csr,
                                                att1 + (size_t)i * DFEAT,
                                                b1 + (size_t)i * DFEAT, R, N);
        hipMemsetAsync(stats, 0, 2 * DFEAT * sizeof(float), stream);
        bn_stats_k<<<256, 256, 0, stream>>>(R, stats, N);
        bn_apply_bf16_k<<<(N * 64 + 255) / 256, 256, 0, stream>>>(
            R, Xb, stats, bn_g + (size_t)i * DFEAT, bn_b + (size_t)i * DFEAT, N);

        // ---- layer 2 ----
        wcast_k<<<(512 * 256 + 255) / 256, 256, 0, stream>>>(
            Wl2 + (size_t)i * DFEAT * DFEAT, Wr2 + (size_t)i * DFEAT * DFEAT, Bt, 256);
        mfma_gemm_k<<<gg, 256, 0, stream>>>(Xb, Bt, C, N, 256);
        gat_gather_k<<<nwave, 256, 0, stream>>>(C, C + 256, offs, csr,
                                                att2 + (size_t)i * DFEAT,
                                                b2 + (size_t)i * DFEAT, R, N);
        hipMemsetAsync(stats, 0, 2 * DFEAT * sizeof(float), stream);
        bn_stats_k<<<256, 256, 0, stream>>>(R, stats, N);
        bn_apply_f32_k<<<(N * 64 + 255) / 256, 256, 0, stream>>>(
            R, R, stats, bn_g + (size_t)i * DFEAT, bn_b + (size_t)i * DFEAT, N);

        // ---- classifier ----
        classifier_k<<<nwave, 256, 0, stream>>>(R, cW, cb, out + out_off, N);
        out_off += (size_t)N * 2;
    }
}

// Round 3
// 834.326 us; speedup vs baseline: 1.8754x; 1.2073x over previous
//
#include <hip/hip_runtime.h>

#define DFEAT 256
#define NEG_ATT 0.2f
#define NEG_ACT 0.01f
#define BN_EPS 1e-5f

typedef short bf16x8 __attribute__((ext_vector_type(8)));
typedef float f32x4 __attribute__((ext_vector_type(4)));

__device__ __forceinline__ float lrelu(float x, float s) { return x > 0.f ? x : s * x; }

__device__ __forceinline__ unsigned short f2bf(float f) {
    union { float f; unsigned int u; } v; v.f = f;
    unsigned int u = v.u;
    unsigned int r = (u + 0x7FFFu + ((u >> 16) & 1u)) >> 16;   // RNE
    return (unsigned short)r;
}
__device__ __forceinline__ float bf2f(unsigned short s) {
    union { unsigned int u; float f; } v; v.u = ((unsigned int)s) << 16;
    return v.f;
}

// ---------------- histogram of dst ----------------
__global__ __launch_bounds__(256)
void hist_k(const int* __restrict__ dst, int E, int* __restrict__ counts) {
    int e = blockIdx.x * 256 + threadIdx.x;
    if (e < E) atomicAdd(&counts[dst[e]], 1);
}

// ---------------- hierarchical exclusive scan (3 kernels) ----------------
__global__ __launch_bounds__(256)
void scan1_k(const int* __restrict__ counts, int* __restrict__ offs,
             int* __restrict__ bsums, int N) {
    __shared__ int buf[256];
    int t = threadIdx.x;
    int i = blockIdx.x * 256 + t;
    int v = (i < N) ? counts[i] : 0;
    buf[t] = v;
    __syncthreads();
    for (int off = 1; off < 256; off <<= 1) {
        int x = (t >= off) ? buf[t - off] : 0;
        __syncthreads();
        buf[t] += x;
        __syncthreads();
    }
    if (i < N) offs[i] = buf[t];            // inclusive within block
    if (t == 255) bsums[blockIdx.x] = buf[255];
}

__global__ __launch_bounds__(256)
void scan2_k(int* __restrict__ bsums, int nb) {   // exclusive scan in place
    __shared__ int buf[256];
    __shared__ int carry_s;
    int t = threadIdx.x;
    if (t == 0) carry_s = 0;
    __syncthreads();
    for (int base = 0; base < nb; base += 256) {
        int i = base + t;
        int v = (i < nb) ? bsums[i] : 0;
        buf[t] = v;
        __syncthreads();
        for (int off = 1; off < 256; off <<= 1) {
            int x = (t >= off) ? buf[t - off] : 0;
            __syncthreads();
            buf[t] += x;
            __syncthreads();
        }
        int incl = buf[t];
        int c = carry_s;
        if (i < nb) bsums[i] = c + incl - v;
        __syncthreads();
        if (t == 255) carry_s = c + buf[255];
        __syncthreads();
    }
}

__global__ __launch_bounds__(256)
void scan3_k(int* __restrict__ offs, const int* __restrict__ counts,
             const int* __restrict__ bsums, int N, int E) {
    int i = blockIdx.x * 256 + threadIdx.x;
    if (i < N) offs[i] = offs[i] - counts[i] + bsums[blockIdx.x];
    if (i == 0) offs[N] = E;
}

// ---------------- scatter edges into CSR (atomicSub restores counts to 0) ----------------
__global__ __launch_bounds__(256)
void scatter_k(const int* __restrict__ src, const int* __restrict__ dst, int E,
               const int* __restrict__ offs, int* __restrict__ cursor,
               int* __restrict__ csr) {
    int e = blockIdx.x * 256 + threadIdx.x;
    if (e >= E) return;
    int d = dst[e];
    int pos = atomicSub(&cursor[d], 1) - 1;   // counts end back at 0 for next type
    csr[offs[d] + pos] = src[e];
}

// ---------------- all weight transposes (bf16) in one dispatch ----------------
__global__ __launch_bounds__(256)
void wcast_all_k(const float* __restrict__ Wl1, const float* __restrict__ Wr1,
                 const float* __restrict__ Wl2, const float* __restrict__ Wr2,
                 unsigned short* __restrict__ Bt1, unsigned short* __restrict__ Bt2) {
    int idx = blockIdx.x * 256 + threadIdx.x;
    const int S1 = 3 * 512 * 128;
    const int S2 = 3 * 512 * 256;
    if (idx < S1) {
        int ty = idx / (512 * 128);
        int r = idx - ty * (512 * 128);
        int n = r >> 7, k = r & 127;
        const float* W = ((n < 256) ? Wl1 : Wr1) + (size_t)ty * 128 * 256;
        Bt1[idx] = f2bf(W[(size_t)k * 256 + (n & 255)]);
    } else if (idx < S1 + S2) {
        int r2 = idx - S1;
        int ty = r2 / (512 * 256);
        int r = r2 - ty * (512 * 256);
        int n = r >> 8, k = r & 255;
        const float* W = ((n < 256) ? Wl2 : Wr2) + (size_t)ty * 256 * 256;
        Bt2[r2] = f2bf(W[(size_t)k * 256 + (n & 255)]);
    }
}

// ---------------- MFMA GEMM: C[M,512] bf16 = A[M,K] @ Bt[512,K]^T ----------------
template<int AF32>
__global__ __launch_bounds__(256)
void mfma_gemm_k(const void* __restrict__ Ap, const unsigned short* __restrict__ Bt,
                 unsigned short* __restrict__ C, int M, int K) {
    const int LDK = 40;                       // padded LDS row stride
    __shared__ unsigned short As[128 * LDK];
    __shared__ unsigned short Bs[128 * LDK];
    int tid = threadIdx.x;
    int bm = blockIdx.x * 128;
    int bn = blockIdx.y * 128;
    int wid = tid >> 6, lane = tid & 63;
    int quad = lane >> 4, l16 = lane & 15;
    int mw = (wid & 1) * 64, nw = (wid >> 1) * 64;
    f32x4 acc[4][4] = {};
    for (int k0 = 0; k0 < K; k0 += 32) {
#pragma unroll
        for (int i = 0; i < 2; ++i) {
            int c = tid + 256 * i;            // 0..511
            int row = c >> 2, ko = (c & 3) * 8;
            int ra = bm + row; if (ra >= M) ra = M - 1;
            if (AF32) {
                const float* Af = (const float*)Ap;
                float4 a0 = *(const float4*)(Af + (size_t)ra * K + k0 + ko);
                float4 a1 = *(const float4*)(Af + (size_t)ra * K + k0 + ko + 4);
                ushort4 lo, hi;
                lo.x = f2bf(a0.x); lo.y = f2bf(a0.y); lo.z = f2bf(a0.z); lo.w = f2bf(a0.w);
                hi.x = f2bf(a1.x); hi.y = f2bf(a1.y); hi.z = f2bf(a1.z); hi.w = f2bf(a1.w);
                *(ushort4*)&As[row * LDK + ko] = lo;
                *(ushort4*)&As[row * LDK + ko + 4] = hi;
            } else {
                const unsigned short* Ab = (const unsigned short*)Ap;
                uint4 va = *(const uint4*)(Ab + (size_t)ra * K + k0 + ko);
                *(uint4*)&As[row * LDK + ko] = va;
            }
            uint4 vb = *(const uint4*)(Bt + (size_t)(bn + row) * K + k0 + ko);
            *(uint4*)&Bs[row * LDK + ko] = vb;
        }
        __syncthreads();
        bf16x8 af[4], bfv[4];
#pragma unroll
        for (int i = 0; i < 4; ++i)
            af[i] = *(bf16x8*)&As[(mw + 16 * i + l16) * LDK + quad * 8];
#pragma unroll
        for (int t = 0; t < 4; ++t)
            bfv[t] = *(bf16x8*)&Bs[(nw + 16 * t + l16) * LDK + quad * 8];
#pragma unroll
        for (int i = 0; i < 4; ++i)
#pragma unroll
            for (int t = 0; t < 4; ++t)
                acc[i][t] = __builtin_amdgcn_mfma_f32_16x16x32_bf16(af[i], bfv[t], acc[i][t], 0, 0, 0);
        __syncthreads();
    }
#pragma unroll
    for (int i = 0; i < 4; ++i) {
#pragma unroll
        for (int r = 0; r < 4; ++r) {
            int grow = bm + mw + 16 * i + quad * 4 + r;
            if (grow < M) {
#pragma unroll
                for (int t = 0; t < 4; ++t) {
                    int gcol = bn + nw + 16 * t + l16;
                    C[(size_t)grow * 512 + gcol] = f2bf(acc[i][t][r]);
                }
            }
        }
    }
}

// ---------------- GATv2 gather: batched prefetch, no-max softmax, bf16 out ----------------
__global__ __launch_bounds__(256)
void gat_gather_k(const unsigned short* __restrict__ hl, const unsigned short* __restrict__ hr,
                  const int* __restrict__ offs, const int* __restrict__ csr,
                  const float* __restrict__ att, const float* __restrict__ bias,
                  unsigned short* __restrict__ out, int N) {
    int wave = (blockIdx.x * 256 + threadIdx.x) >> 6;
    int lane = threadIdx.x & 63;
    if (wave >= N) return;
    int d = wave;
    int f4 = lane << 2;                 // features f4..f4+3, head = lane>>4
    ushort4 hru = *(const ushort4*)(hr + (size_t)d * 512 + f4);
    float hr0 = bf2f(hru.x), hr1 = bf2f(hru.y), hr2 = bf2f(hru.z), hr3 = bf2f(hru.w);
    float4 av  = *(const float4*)(att + f4);
    float4 bv  = *(const float4*)(bias + f4);
    float l = 0.f, ac0 = 0.f, ac1 = 0.f, ac2 = 0.f, ac3 = 0.f;

    auto update = [&](ushort4 u) {
        float h0 = bf2f(u.x), h1 = bf2f(u.y), h2 = bf2f(u.z), h3 = bf2f(u.w);
        float e0 = lrelu(h0 + hr0, NEG_ATT);
        float e1 = lrelu(h1 + hr1, NEG_ATT);
        float e2 = lrelu(h2 + hr2, NEG_ATT);
        float e3 = lrelu(h3 + hr3, NEG_ATT);
        float part = e0 * av.x + e1 * av.y + e2 * av.z + e3 * av.w;
        part += __shfl_xor(part, 1, 16);
        part += __shfl_xor(part, 2, 16);
        part += __shfl_xor(part, 4, 16);
        part += __shfl_xor(part, 8, 16);
        float p = __expf(part);          // |score| ~< 4: overflow-safe, softmax shift-invariant
        l += p;
        ac0 += p * h0; ac1 += p * h1; ac2 += p * h2; ac3 += p * h3;
    };

    // self-loop
    update(*(const ushort4*)(hl + (size_t)d * 512 + f4));

    int beg = offs[d], end = offs[d + 1];
    int deg = end - beg;
    for (int base = 0; base < deg; base += 64) {
        int cnt = min(64, deg - base);
        int my = (base + lane < deg) ? csr[beg + base + lane] : d;
        for (int j = 0; j < cnt; j += 4) {
            int kk = min(4, cnt - j);
            ushort4 v[4];
#pragma unroll
            for (int t = 0; t < 4; ++t) {
                int s = __shfl(my, (j + t) & 63);
                if (t < kk) v[t] = *(const ushort4*)(hl + (size_t)s * 512 + f4);
            }
#pragma unroll
            for (int t = 0; t < 4; ++t)
                if (t < kk) update(v[t]);
        }
    }
    float inv = 1.f / (l + 1e-16f);
    ushort4 o;
    o.x = f2bf(ac0 * inv + bv.x);
    o.y = f2bf(ac1 * inv + bv.y);
    o.z = f2bf(ac2 * inv + bv.z);
    o.w = f2bf(ac3 * inv + bv.w);
    *(ushort4*)(out + (size_t)d * DFEAT + f4) = o;
}

// ---------------- BatchNorm stats from bf16 ----------------
__global__ __launch_bounds__(256)
void bn_stats_bf16_k(const unsigned short* __restrict__ h, float* __restrict__ stats, int N) {
    int f = threadIdx.x;                      // 0..255
    float s = 0.f, s2 = 0.f;
    for (int r = blockIdx.x; r < N; r += gridDim.x) {
        float v = bf2f(h[(size_t)r * DFEAT + f]);
        s += v; s2 += v * v;
    }
    atomicAdd(&stats[f], s);
    atomicAdd(&stats[DFEAT + f], s2);
}

// ---------------- BatchNorm apply + leaky_relu, bf16 in -> bf16 out ----------------
__global__ __launch_bounds__(256)
void bn_apply_bf16_k(const unsigned short* __restrict__ in, unsigned short* __restrict__ outp,
                     const float* __restrict__ stats, const float* __restrict__ g,
                     const float* __restrict__ b, int N) {
    size_t idx = (size_t)blockIdx.x * 256 + threadIdx.x;   // ushort4 index
    if (idx >= (size_t)N * 64) return;
    int f4 = ((int)(idx & 63)) << 2;
    float invN = 1.f / (float)N;
    ushort4 u = ((const ushort4*)in)[idx];
    float vv[4] = {bf2f(u.x), bf2f(u.y), bf2f(u.z), bf2f(u.w)};
    ushort4 ov;
    unsigned short* op = (unsigned short*)&ov;
#pragma unroll
    for (int j = 0; j < 4; ++j) {
        int f = f4 + j;
        float mu  = stats[f] * invN;
        float var = stats[DFEAT + f] * invN - mu * mu;
        float sc  = g[f] / sqrtf(var + BN_EPS);
        float val = (vv[j] - mu) * sc + b[f];
        op[j] = f2bf(lrelu(val, NEG_ACT));
    }
    ((ushort4*)outp)[idx] = ov;
}

// ---------------- fused BN + leaky_relu + classifier: one wave per node ----------------
__global__ __launch_bounds__(256)
void bn_cls_k(const unsigned short* __restrict__ R, const float* __restrict__ stats,
              const float* __restrict__ g, const float* __restrict__ b,
              const float* __restrict__ cW, const float* __restrict__ cb,
              float* __restrict__ out, int N) {
    int wave = (blockIdx.x * 256 + threadIdx.x) >> 6;
    int lane = threadIdx.x & 63;
    if (wave >= N) return;
    int f4 = lane << 2;
    float invN = 1.f / (float)N;
    ushort4 u = *(const ushort4*)(R + (size_t)wave * DFEAT + f4);
    float vv[4] = {bf2f(u.x), bf2f(u.y), bf2f(u.z), bf2f(u.w)};
    float p0 = 0.f, p1 = 0.f;
#pragma unroll
    for (int j = 0; j < 4; ++j) {
        int f = f4 + j;
        float mu  = stats[f] * invN;
        float var = stats[DFEAT + f] * invN - mu * mu;
        float sc  = g[f] / sqrtf(var + BN_EPS);
        float val = lrelu((vv[j] - mu) * sc + b[f], NEG_ACT);
        float2 w = *(const float2*)(cW + (size_t)f * 2);
        p0 += val * w.x;
        p1 += val * w.y;
    }
#pragma unroll
    for (int off = 1; off < 64; off <<= 1) {
        p0 += __shfl_xor(p0, off);
        p1 += __shfl_xor(p1, off);
    }
    if (lane == 0) {
        out[(size_t)wave * 2 + 0] = p0 + cb[0];
        out[(size_t)wave * 2 + 1] = p1 + cb[1];
    }
}

extern "C" void kernel_launch(void* const* d_in, const int* in_sizes, int n_in,
                              void* d_out, int out_size, void* d_ws, size_t ws_size,
                              hipStream_t stream) {
    const float* x[3]  = {(const float*)d_in[0], (const float*)d_in[1], (const float*)d_in[2]};
    const int*   ei[3] = {(const int*)d_in[3], (const int*)d_in[4], (const int*)d_in[5]};
    const float* Wl1 = (const float*)d_in[6];
    const float* Wr1 = (const float*)d_in[7];
    const float* att1 = (const float*)d_in[8];
    const float* b1 = (const float*)d_in[9];
    const float* Wl2 = (const float*)d_in[10];
    const float* Wr2 = (const float*)d_in[11];
    const float* att2 = (const float*)d_in[12];
    const float* b2 = (const float*)d_in[13];
    const float* bn_g = (const float*)d_in[14];
    const float* bn_b = (const float*)d_in[15];
    const float* cW = (const float*)d_in[16];
    const float* cb = (const float*)d_in[17];

    int Ns[3] = {in_sizes[0] / 128, in_sizes[1] / 128, in_sizes[2] / 128};
    int Es[3] = {in_sizes[3] / 2, in_sizes[4] / 2, in_sizes[5] / 2};
    int maxN = Ns[0], maxE = Es[0];
    for (int i = 1; i < 3; ++i) {
        if (Ns[i] > maxN) maxN = Ns[i];
        if (Es[i] > maxE) maxE = Es[i];
    }

    char* w = (char*)d_ws;
    auto alloc_b = [&](size_t bytes) -> void* {
        void* p = (void*)w;
        w += (bytes + 255) & ~(size_t)255;
        return p;
    };
    unsigned short* Xb = (unsigned short*)alloc_b((size_t)maxN * DFEAT * sizeof(unsigned short)); // GEMM-A bf16 (layer2)
    unsigned short* C  = (unsigned short*)alloc_b((size_t)maxN * 512 * sizeof(unsigned short));   // GEMM out hl||hr
    unsigned short* Rb = (unsigned short*)alloc_b((size_t)maxN * DFEAT * sizeof(unsigned short)); // gather out bf16
    unsigned short* Bt1 = (unsigned short*)alloc_b((size_t)3 * 512 * 128 * sizeof(unsigned short));
    unsigned short* Bt2 = (unsigned short*)alloc_b((size_t)3 * 512 * 256 * sizeof(unsigned short));
    int* counts = (int*)alloc_b((size_t)maxN * sizeof(int));
    int* offs   = (int*)alloc_b((size_t)(maxN + 1) * sizeof(int));
    int* csr    = (int*)alloc_b((size_t)maxE * sizeof(int));
    int* bsums  = (int*)alloc_b(((size_t)(maxN + 255) / 256) * sizeof(int));
    float* stats_all = (float*)alloc_b((size_t)6 * 512 * sizeof(float));

    float* out = (float*)d_out;
    size_t out_off = 0;

    // one-time global prep
    hipMemsetAsync(counts, 0, (size_t)maxN * sizeof(int), stream);
    hipMemsetAsync(stats_all, 0, (size_t)6 * 512 * sizeof(float), stream);
    {
        int tot = 3 * 512 * 128 + 3 * 512 * 256;
        wcast_all_k<<<(tot + 255) / 256, 256, 0, stream>>>(Wl1, Wr1, Wl2, Wr2, Bt1, Bt2);
    }

    for (int i = 0; i < 3; ++i) {
        int N = Ns[i], E = Es[i];
        const int* src = ei[i];
        const int* dst = ei[i] + E;
        int nblkN = (N + 255) / 256;
        int nblkE = (E + 255) / 256;
        int nwave = (N + 3) / 4;
        float* st1 = stats_all + (size_t)(i * 2 + 0) * 512;
        float* st2 = stats_all + (size_t)(i * 2 + 1) * 512;

        // ---- CSR build (counts is all-zero on entry; scatter restores it) ----
        hist_k<<<nblkE, 256, 0, stream>>>(dst, E, counts);
        scan1_k<<<nblkN, 256, 0, stream>>>(counts, offs, bsums, N);
        scan2_k<<<1, 256, 0, stream>>>(bsums, nblkN);
        scan3_k<<<nblkN, 256, 0, stream>>>(offs, counts, bsums, N, E);
        scatter_k<<<nblkE, 256, 0, stream>>>(src, dst, E, offs, counts, csr);

        dim3 gg((N + 127) / 128, 4);

        // ---- layer 1 (A = x fp32, staged-cast inside GEMM) ----
        mfma_gemm_k<1><<<gg, 256, 0, stream>>>(x[i], Bt1 + (size_t)i * 512 * 128, C, N, 128);
        gat_gather_k<<<nwave, 256, 0, stream>>>(C, C + 256, offs, csr,
                                                att1 + (size_t)i * DFEAT,
                                                b1 + (size_t)i * DFEAT, Rb, N);
        bn_stats_bf16_k<<<256, 256, 0, stream>>>(Rb, st1, N);
        bn_apply_bf16_k<<<(N * 64 + 255) / 256, 256, 0, stream>>>(
            Rb, Xb, st1, bn_g + (size_t)i * DFEAT, bn_b + (size_t)i * DFEAT, N);

        // ---- layer 2 ----
        mfma_gemm_k<0><<<gg, 256, 0, stream>>>(Xb, Bt2 + (size_t)i * 512 * 256, C, N, 256);
        gat_gather_k<<<nwave, 256, 0, stream>>>(C, C + 256, offs, csr,
                                                att2 + (size_t)i * DFEAT,
                                                b2 + (size_t)i * DFEAT, Rb, N);
        bn_stats_bf16_k<<<256, 256, 0, stream>>>(Rb, st2, N);

        // ---- fused BN + lrelu + classifier ----
        bn_cls_k<<<nwave, 256, 0, stream>>>(Rb, st2,
                                            bn_g + (size_t)i * DFEAT, bn_b + (size_t)i * DFEAT,
                                            cW, cb, out + out_off, N);
        out_off += (size_t)N * 2;
    }
}

// Round 5
// 581.227 us; speedup vs baseline: 2.6921x; 1.4355x over previous
//
#include <hip/hip_runtime.h>

#define DFEAT 256
#define NEG_ATT 0.2f
#define NEG_ACT 0.01f
#define BN_EPS 1e-5f

typedef short bf16x8 __attribute__((ext_vector_type(8)));
typedef float f32x4 __attribute__((ext_vector_type(4)));

struct Int3 { int a[3]; };
struct Cp3 { const void* p[3]; };
struct Vp3 { void* p[3]; };

__device__ __forceinline__ float lrelu(float x, float s) { return x > 0.f ? x : s * x; }

__device__ __forceinline__ unsigned short f2bf(float f) {
    union { float f; unsigned int u; } v; v.f = f;
    unsigned int u = v.u;
    unsigned int r = (u + 0x7FFFu + ((u >> 16) & 1u)) >> 16;   // RNE
    return (unsigned short)r;
}
__device__ __forceinline__ float bf2f(unsigned short s) {
    union { unsigned int u; float f; } v; v.u = ((unsigned int)s) << 16;
    return v.f;
}

// ---------------- histogram of dst (all types) ----------------
__global__ __launch_bounds__(256)
void hist_all_k(Cp3 dst, Int3 E, int* __restrict__ counts_all, Int3 nodeOff) {
    int t = blockIdx.y;
    int e = blockIdx.x * 256 + threadIdx.x;
    if (e >= E.a[t]) return;
    const int* dstp = (const int*)dst.p[t];
    atomicAdd(&counts_all[nodeOff.a[t] + dstp[e]], 1);
}

// ---------------- hierarchical exclusive scan (all types) ----------------
__global__ __launch_bounds__(256)
void scan1_all_k(const int* __restrict__ counts_all, int* __restrict__ offs_all,
                 int* __restrict__ bsums_all, Int3 N, Int3 nodeOff, Int3 bOff) {
    int t = blockIdx.y;
    if (blockIdx.x * 256 >= N.a[t]) return;
    const int* counts = counts_all + nodeOff.a[t];
    int* offs = offs_all + nodeOff.a[t] + t;
    int* bsums = bsums_all + bOff.a[t];
    __shared__ int buf[256];
    int tt = threadIdx.x;
    int i = blockIdx.x * 256 + tt;
    int v = (i < N.a[t]) ? counts[i] : 0;
    buf[tt] = v;
    __syncthreads();
    for (int off = 1; off < 256; off <<= 1) {
        int x = (tt >= off) ? buf[tt - off] : 0;
        __syncthreads();
        buf[tt] += x;
        __syncthreads();
    }
    if (i < N.a[t]) offs[i] = buf[tt];            // inclusive within block
    if (tt == 255) bsums[blockIdx.x] = buf[255];
}

__global__ __launch_bounds__(256)
void scan2_all_k(int* __restrict__ bsums_all, Int3 N, Int3 bOff) {
    int t = blockIdx.x;
    int nb = (N.a[t] + 255) / 256;
    int* bsums = bsums_all + bOff.a[t];
    __shared__ int buf[256];
    __shared__ int carry_s;
    int tt = threadIdx.x;
    if (tt == 0) carry_s = 0;
    __syncthreads();
    for (int base = 0; base < nb; base += 256) {
        int i = base + tt;
        int v = (i < nb) ? bsums[i] : 0;
        buf[tt] = v;
        __syncthreads();
        for (int off = 1; off < 256; off <<= 1) {
            int x = (tt >= off) ? buf[tt - off] : 0;
            __syncthreads();
            buf[tt] += x;
            __syncthreads();
        }
        int incl = buf[tt];
        int c = carry_s;
        if (i < nb) bsums[i] = c + incl - v;
        __syncthreads();
        if (tt == 255) carry_s = c + buf[255];
        __syncthreads();
    }
}

__global__ __launch_bounds__(256)
void scan3_all_k(int* __restrict__ offs_all, const int* __restrict__ counts_all,
                 const int* __restrict__ bsums_all, Int3 N, Int3 E,
                 Int3 nodeOff, Int3 bOff) {
    int t = blockIdx.y;
    if (blockIdx.x * 256 >= N.a[t]) return;
    int* offs = offs_all + nodeOff.a[t] + t;
    const int* counts = counts_all + nodeOff.a[t];
    const int* bsums = bsums_all + bOff.a[t];
    int i = blockIdx.x * 256 + threadIdx.x;
    if (i < N.a[t]) offs[i] = offs[i] - counts[i] + bsums[blockIdx.x];
    if (i == 0) offs[N.a[t]] = E.a[t];
}

// ---------------- scatter edges into CSR (atomicSub restores counts to 0) ----------------
__global__ __launch_bounds__(256)
void scatter_all_k(Cp3 src, Cp3 dst, Int3 E, const int* __restrict__ offs_all,
                   int* __restrict__ counts_all, int* __restrict__ csr_all,
                   Int3 nodeOff, Int3 edgeOff) {
    int t = blockIdx.y;
    int e = blockIdx.x * 256 + threadIdx.x;
    if (e >= E.a[t]) return;
    const int* srcp = (const int*)src.p[t];
    const int* dstp = (const int*)dst.p[t];
    const int* offs = offs_all + nodeOff.a[t] + t;
    int* cursor = counts_all + nodeOff.a[t];
    int* csr = csr_all + edgeOff.a[t];
    int d = dstp[e];
    int pos = atomicSub(&cursor[d], 1) - 1;   // counts end back at 0
    csr[offs[d] + pos] = srcp[e];
}

// ---------------- all weight transposes (bf16) in one dispatch ----------------
__global__ __launch_bounds__(256)
void wcast_all_k(const float* __restrict__ Wl1, const float* __restrict__ Wr1,
                 const float* __restrict__ Wl2, const float* __restrict__ Wr2,
                 unsigned short* __restrict__ Bt1, unsigned short* __restrict__ Bt2) {
    int idx = blockIdx.x * 256 + threadIdx.x;
    const int S1 = 3 * 512 * 128;
    const int S2 = 3 * 512 * 256;
    if (idx < S1) {
        int ty = idx / (512 * 128);
        int r = idx - ty * (512 * 128);
        int n = r >> 7, k = r & 127;
        const float* W = ((n < 256) ? Wl1 : Wr1) + (size_t)ty * 128 * 256;
        Bt1[idx] = f2bf(W[(size_t)k * 256 + (n & 255)]);
    } else if (idx < S1 + S2) {
        int r2 = idx - S1;
        int ty = r2 / (512 * 256);
        int r = r2 - ty * (512 * 256);
        int n = r >> 8, k = r & 255;
        const float* W = ((n < 256) ? Wl2 : Wr2) + (size_t)ty * 256 * 256;
        Bt2[r2] = f2bf(W[(size_t)k * 256 + (n & 255)]);
    }
}

// ---------------- MFMA GEMM (all types): C[M,512] bf16 = A[M,K] @ Bt[512,K]^T ----------------
template<int AF32>
__global__ __launch_bounds__(256)
void mfma_gemm_all_k(Cp3 Ap3, Cp3 Bp3, Vp3 Cp3v, Int3 M3, int K) {
    int t = blockIdx.z;
    int M = M3.a[t];
    int bm = blockIdx.x * 128;
    if (bm >= M) return;
    const void* Ap = Ap3.p[t];
    const unsigned short* Bt = (const unsigned short*)Bp3.p[t];
    unsigned short* C = (unsigned short*)Cp3v.p[t];
    const int LDK = 40;                       // padded LDS row stride
    __shared__ unsigned short As[128 * LDK];
    __shared__ unsigned short Bs[128 * LDK];
    int tid = threadIdx.x;
    int bn = blockIdx.y * 128;
    int wid = tid >> 6, lane = tid & 63;
    int quad = lane >> 4, l16 = lane & 15;
    int mw = (wid & 1) * 64, nw = (wid >> 1) * 64;
    f32x4 acc[4][4] = {};
    for (int k0 = 0; k0 < K; k0 += 32) {
#pragma unroll
        for (int i = 0; i < 2; ++i) {
            int c = tid + 256 * i;            // 0..511
            int row = c >> 2, ko = (c & 3) * 8;
            int ra = bm + row; if (ra >= M) ra = M - 1;
            if (AF32) {
                const float* Af = (const float*)Ap;
                float4 a0 = *(const float4*)(Af + (size_t)ra * K + k0 + ko);
                float4 a1 = *(const float4*)(Af + (size_t)ra * K + k0 + ko + 4);
                ushort4 lo, hi;
                lo.x = f2bf(a0.x); lo.y = f2bf(a0.y); lo.z = f2bf(a0.z); lo.w = f2bf(a0.w);
                hi.x = f2bf(a1.x); hi.y = f2bf(a1.y); hi.z = f2bf(a1.z); hi.w = f2bf(a1.w);
                *(ushort4*)&As[row * LDK + ko] = lo;
                *(ushort4*)&As[row * LDK + ko + 4] = hi;
            } else {
                const unsigned short* Ab = (const unsigned short*)Ap;
                uint4 va = *(const uint4*)(Ab + (size_t)ra * K + k0 + ko);
                *(uint4*)&As[row * LDK + ko] = va;
            }
            uint4 vb = *(const uint4*)(Bt + (size_t)(bn + row) * K + k0 + ko);
            *(uint4*)&Bs[row * LDK + ko] = vb;
        }
        __syncthreads();
        bf16x8 af[4], bfv[4];
#pragma unroll
        for (int i = 0; i < 4; ++i)
            af[i] = *(bf16x8*)&As[(mw + 16 * i + l16) * LDK + quad * 8];
#pragma unroll
        for (int u = 0; u < 4; ++u)
            bfv[u] = *(bf16x8*)&Bs[(nw + 16 * u + l16) * LDK + quad * 8];
#pragma unroll
        for (int i = 0; i < 4; ++i)
#pragma unroll
            for (int u = 0; u < 4; ++u)
                acc[i][u] = __builtin_amdgcn_mfma_f32_16x16x32_bf16(af[i], bfv[u], acc[i][u], 0, 0, 0);
        __syncthreads();
    }
#pragma unroll
    for (int i = 0; i < 4; ++i) {
#pragma unroll
        for (int r = 0; r < 4; ++r) {
            int grow = bm + mw + 16 * i + quad * 4 + r;
            if (grow < M) {
#pragma unroll
                for (int u = 0; u < 4; ++u) {
                    int gcol = bn + nw + 16 * u + l16;
                    C[(size_t)grow * 512 + gcol] = f2bf(acc[i][u][r]);
                }
            }
        }
    }
}

// ---------------- GATv2 gather (all types): batch-8 prefetch, no-max softmax ----------------
__global__ __launch_bounds__(256)
void gat_gather_all_k(Cp3 hl3, Cp3 offs3, Cp3 csr3, Cp3 att3, Cp3 bias3,
                      Vp3 out3, Int3 N3) {
    int t = blockIdx.z;
    int N = N3.a[t];
    int wave = (blockIdx.x * 256 + threadIdx.x) >> 6;
    int lane = threadIdx.x & 63;
    if (wave >= N) return;
    const unsigned short* hl = (const unsigned short*)hl3.p[t];
    const unsigned short* hr = hl + 256;
    const int* offs = (const int*)offs3.p[t];
    const int* csr = (const int*)csr3.p[t];
    const float* att = (const float*)att3.p[t];
    const float* bias = (const float*)bias3.p[t];
    unsigned short* out = (unsigned short*)out3.p[t];
    int d = wave;
    int f4 = lane << 2;                 // features f4..f4+3, head = lane>>4
    ushort4 hru = *(const ushort4*)(hr + (size_t)d * 512 + f4);
    float hr0 = bf2f(hru.x), hr1 = bf2f(hru.y), hr2 = bf2f(hru.z), hr3 = bf2f(hru.w);
    float4 av  = *(const float4*)(att + f4);
    float4 bv  = *(const float4*)(bias + f4);
    float l = 0.f, ac0 = 0.f, ac1 = 0.f, ac2 = 0.f, ac3 = 0.f;

    auto update = [&](ushort4 u) {
        float h0 = bf2f(u.x), h1 = bf2f(u.y), h2 = bf2f(u.z), h3 = bf2f(u.w);
        float e0 = lrelu(h0 + hr0, NEG_ATT);
        float e1 = lrelu(h1 + hr1, NEG_ATT);
        float e2 = lrelu(h2 + hr2, NEG_ATT);
        float e3 = lrelu(h3 + hr3, NEG_ATT);
        float part = e0 * av.x + e1 * av.y + e2 * av.z + e3 * av.w;
        part += __shfl_xor(part, 1, 16);
        part += __shfl_xor(part, 2, 16);
        part += __shfl_xor(part, 4, 16);
        part += __shfl_xor(part, 8, 16);
        float p = __expf(part);          // |score| small: overflow-safe, softmax shift-invariant
        l += p;
        ac0 += p * h0; ac1 += p * h1; ac2 += p * h2; ac3 += p * h3;
    };

    update(*(const ushort4*)(hl + (size_t)d * 512 + f4));   // self-loop

    int beg = offs[d], end = offs[d + 1];
    int deg = end - beg;
    for (int base = 0; base < deg; base += 64) {
        int cnt = min(64, deg - base);
        int my = (base + lane < deg) ? csr[beg + base + lane] : d;
        for (int j = 0; j < cnt; j += 8) {
            int kk = min(8, cnt - j);
            ushort4 v[8];
#pragma unroll
            for (int u = 0; u < 8; ++u) {
                int s = __shfl(my, (j + u) & 63);
                if (u < kk) v[u] = *(const ushort4*)(hl + (size_t)s * 512 + f4);
            }
#pragma unroll
            for (int u = 0; u < 8; ++u)
                if (u < kk) update(v[u]);
        }
    }
    float inv = 1.f / (l + 1e-16f);
    ushort4 o;
    o.x = f2bf(ac0 * inv + bv.x);
    o.y = f2bf(ac1 * inv + bv.y);
    o.z = f2bf(ac2 * inv + bv.z);
    o.w = f2bf(ac3 * inv + bv.w);
    *(ushort4*)(out + (size_t)d * DFEAT + f4) = o;
}

// ---------------- BN stats (all types): vectorized ushort8 loads ----------------
__global__ __launch_bounds__(256)
void bn_stats_all_k(Cp3 h3, Vp3 st3, Int3 N3) {
    int t = blockIdx.y;
    const unsigned short* hp = (const unsigned short*)h3.p[t];
    float* st = (float*)st3.p[t];
    long total = (long)N3.a[t] * 256;
    int tid = threadIdx.x;
    long gt = (long)blockIdx.x * 256 + tid;
    long stride = (long)gridDim.x * 256 * 8;
    float s[8] = {0.f}, s2[8] = {0.f};
    for (long p = gt * 8; p < total; p += stride) {
        uint4 u = *(const uint4*)(hp + p);
        unsigned short* us = (unsigned short*)&u;   // 8 bf16
#pragma unroll
        for (int j = 0; j < 8; ++j) { float v = bf2f(us[j]); s[j] += v; s2[j] += v * v; }
    }
#pragma unroll
    for (int j = 0; j < 8; ++j) { s[j] += __shfl_xor(s[j], 32); s2[j] += __shfl_xor(s2[j], 32); }
    __shared__ float lds[2048];
    int wv = tid >> 6, lane = tid & 63;
    if (lane < 32) {
#pragma unroll
        for (int j = 0; j < 8; ++j) {
            lds[wv * 512 + lane * 8 + j] = s[j];
            lds[wv * 512 + 256 + lane * 8 + j] = s2[j];
        }
    }
    __syncthreads();
    // FIX (round 4 NaN): block has 256 threads, need to cover 512 stat slots
    for (int q = tid; q < 512; q += 256) {
        float v = lds[q] + lds[512 + q] + lds[1024 + q] + lds[1536 + q];
        atomicAdd(&st[q], v);
    }
}

// ---------------- BN apply + leaky_relu (all types), in-place bf16 ----------------
__global__ __launch_bounds__(256)
void bn_apply_all_k(Vp3 h3, Cp3 st3, const float* __restrict__ gb, const float* __restrict__ bb,
                    Int3 N3) {
    int t = blockIdx.y;
    int N = N3.a[t];
    size_t idx = (size_t)blockIdx.x * 256 + threadIdx.x;   // ushort4 index
    if (idx >= (size_t)N * 64) return;
    unsigned short* h = (unsigned short*)h3.p[t];
    const float* stats = (const float*)st3.p[t];
    const float* g = gb + (size_t)t * DFEAT;
    const float* b = bb + (size_t)t * DFEAT;
    int f4 = ((int)(idx & 63)) << 2;
    float invN = 1.f / (float)N;
    ushort4 u = ((const ushort4*)h)[idx];
    float vv[4] = {bf2f(u.x), bf2f(u.y), bf2f(u.z), bf2f(u.w)};
    ushort4 ov;
    unsigned short* op = (unsigned short*)&ov;
#pragma unroll
    for (int j = 0; j < 4; ++j) {
        int f = f4 + j;
        float mu  = stats[f] * invN;
        float var = stats[DFEAT + f] * invN - mu * mu;
        float sc  = g[f] / sqrtf(var + BN_EPS);
        float val = (vv[j] - mu) * sc + b[f];
        op[j] = f2bf(lrelu(val, NEG_ACT));
    }
    ((ushort4*)h)[idx] = ov;
}

// ---------------- fused BN + leaky_relu + classifier (all types) ----------------
__global__ __launch_bounds__(256)
void bn_cls_all_k(Cp3 R3, Cp3 st3, const float* __restrict__ gb, const float* __restrict__ bb,
                  const float* __restrict__ cW, const float* __restrict__ cb,
                  Vp3 out3, Int3 N3) {
    int t = blockIdx.y;
    int N = N3.a[t];
    int wave = (blockIdx.x * 256 + threadIdx.x) >> 6;
    int lane = threadIdx.x & 63;
    if (wave >= N) return;
    const unsigned short* R = (const unsigned short*)R3.p[t];
    const float* stats = (const float*)st3.p[t];
    const float* g = gb + (size_t)t * DFEAT;
    const float* b = bb + (size_t)t * DFEAT;
    float* out = (float*)out3.p[t];
    int f4 = lane << 2;
    float invN = 1.f / (float)N;
    ushort4 u = *(const ushort4*)(R + (size_t)wave * DFEAT + f4);
    float vv[4] = {bf2f(u.x), bf2f(u.y), bf2f(u.z), bf2f(u.w)};
    float p0 = 0.f, p1 = 0.f;
#pragma unroll
    for (int j = 0; j < 4; ++j) {
        int f = f4 + j;
        float mu  = stats[f] * invN;
        float var = stats[DFEAT + f] * invN - mu * mu;
        float sc  = g[f] / sqrtf(var + BN_EPS);
        float val = lrelu((vv[j] - mu) * sc + b[f], NEG_ACT);
        float2 w = *(const float2*)(cW + (size_t)f * 2);
        p0 += val * w.x;
        p1 += val * w.y;
    }
#pragma unroll
    for (int off = 1; off < 64; off <<= 1) {
        p0 += __shfl_xor(p0, off);
        p1 += __shfl_xor(p1, off);
    }
    if (lane == 0) {
        out[(size_t)wave * 2 + 0] = p0 + cb[0];
        out[(size_t)wave * 2 + 1] = p1 + cb[1];
    }
}

extern "C" void kernel_launch(void* const* d_in, const int* in_sizes, int n_in,
                              void* d_out, int out_size, void* d_ws, size_t ws_size,
                              hipStream_t stream) {
    const float* x0 = (const float*)d_in[0];
    const float* x1 = (const float*)d_in[1];
    const float* x2 = (const float*)d_in[2];
    const int* ei[3] = {(const int*)d_in[3], (const int*)d_in[4], (const int*)d_in[5]};
    const float* Wl1 = (const float*)d_in[6];
    const float* Wr1 = (const float*)d_in[7];
    const float* att1 = (const float*)d_in[8];
    const float* b1 = (const float*)d_in[9];
    const float* Wl2 = (const float*)d_in[10];
    const float* Wr2 = (const float*)d_in[11];
    const float* att2 = (const float*)d_in[12];
    const float* b2 = (const float*)d_in[13];
    const float* bn_g = (const float*)d_in[14];
    const float* bn_b = (const float*)d_in[15];
    const float* cW = (const float*)d_in[16];
    const float* cb = (const float*)d_in[17];

    Int3 N3, E3, nodeOff, edgeOff, bOff;
    N3.a[0] = in_sizes[0] / 128; N3.a[1] = in_sizes[1] / 128; N3.a[2] = in_sizes[2] / 128;
    E3.a[0] = in_sizes[3] / 2;   E3.a[1] = in_sizes[4] / 2;   E3.a[2] = in_sizes[5] / 2;
    int Ntot = 0, Etot = 0, btot = 0;
    int maxN = 0, maxE = 0;
    for (int i = 0; i < 3; ++i) {
        nodeOff.a[i] = Ntot; edgeOff.a[i] = Etot; bOff.a[i] = btot;
        Ntot += N3.a[i]; Etot += E3.a[i]; btot += (N3.a[i] + 255) / 256;
        if (N3.a[i] > maxN) maxN = N3.a[i];
        if (E3.a[i] > maxE) maxE = E3.a[i];
    }

    char* w = (char*)d_ws;
    auto alloc_b = [&](size_t bytes) -> void* {
        void* p = (void*)w;
        w += (bytes + 255) & ~(size_t)255;
        return p;
    };
    unsigned short* C_all  = (unsigned short*)alloc_b((size_t)Ntot * 512 * sizeof(unsigned short));
    unsigned short* Rb_all = (unsigned short*)alloc_b((size_t)Ntot * DFEAT * sizeof(unsigned short));
    unsigned short* Bt1 = (unsigned short*)alloc_b((size_t)3 * 512 * 128 * sizeof(unsigned short));
    unsigned short* Bt2 = (unsigned short*)alloc_b((size_t)3 * 512 * 256 * sizeof(unsigned short));
    int* counts_all = (int*)alloc_b((size_t)Ntot * sizeof(int));
    int* offs_all   = (int*)alloc_b((size_t)(Ntot + 3) * sizeof(int));
    int* csr_all    = (int*)alloc_b((size_t)Etot * sizeof(int));
    int* bsums_all  = (int*)alloc_b((size_t)btot * sizeof(int));
    float* stats_all = (float*)alloc_b((size_t)6 * 512 * sizeof(float));

    // per-type pointer packs
    Cp3 srcP, dstP, xP, Bt1P, Bt2P, hlP, offsP, csrP, att1P, att2P, b1P, b2P;
    Cp3 RbCP, st1CP, st2CP;
    Vp3 CP, RbP, st1P, st2P, outP;
    for (int i = 0; i < 3; ++i) {
        srcP.p[i] = ei[i];
        dstP.p[i] = ei[i] + E3.a[i];
        xP.p[i] = (i == 0) ? (const void*)x0 : (i == 1) ? (const void*)x1 : (const void*)x2;
        Bt1P.p[i] = Bt1 + (size_t)i * 512 * 128;
        Bt2P.p[i] = Bt2 + (size_t)i * 512 * 256;
        CP.p[i] = C_all + (size_t)nodeOff.a[i] * 512;
        hlP.p[i] = CP.p[i];
        RbP.p[i] = Rb_all + (size_t)nodeOff.a[i] * DFEAT;
        RbCP.p[i] = RbP.p[i];
        offsP.p[i] = offs_all + nodeOff.a[i] + i;
        csrP.p[i] = csr_all + edgeOff.a[i];
        att1P.p[i] = att1 + (size_t)i * DFEAT;
        att2P.p[i] = att2 + (size_t)i * DFEAT;
        b1P.p[i] = b1 + (size_t)i * DFEAT;
        b2P.p[i] = b2 + (size_t)i * DFEAT;
        st1P.p[i] = stats_all + (size_t)i * 512;
        st2P.p[i] = stats_all + (size_t)(3 + i) * 512;
        st1CP.p[i] = st1P.p[i];
        st2CP.p[i] = st2P.p[i];
        outP.p[i] = (float*)d_out + (size_t)nodeOff.a[i] * 2;
    }

    int maxNblk = (maxN + 255) / 256;
    int maxEblk = (maxE + 255) / 256;
    int maxMtile = (maxN + 127) / 128;
    int maxNwave = (maxN + 3) / 4;

    // one-time prep
    hipMemsetAsync(counts_all, 0, (size_t)Ntot * sizeof(int), stream);
    hipMemsetAsync(stats_all, 0, (size_t)6 * 512 * sizeof(float), stream);
    {
        int tot = 3 * 512 * 128 + 3 * 512 * 256;
        wcast_all_k<<<(tot + 255) / 256, 256, 0, stream>>>(Wl1, Wr1, Wl2, Wr2, Bt1, Bt2);
    }

    // ---- CSR build (all types) ----
    hist_all_k<<<dim3(maxEblk, 3), 256, 0, stream>>>(dstP, E3, counts_all, nodeOff);
    scan1_all_k<<<dim3(maxNblk, 3), 256, 0, stream>>>(counts_all, offs_all, bsums_all, N3, nodeOff, bOff);
    scan2_all_k<<<3, 256, 0, stream>>>(bsums_all, N3, bOff);
    scan3_all_k<<<dim3(maxNblk, 3), 256, 0, stream>>>(offs_all, counts_all, bsums_all, N3, E3, nodeOff, bOff);
    scatter_all_k<<<dim3(maxEblk, 3), 256, 0, stream>>>(srcP, dstP, E3, offs_all, counts_all, csr_all, nodeOff, edgeOff);

    // ---- layer 1 ----
    mfma_gemm_all_k<1><<<dim3(maxMtile, 4, 3), 256, 0, stream>>>(xP, Bt1P, CP, N3, 128);
    gat_gather_all_k<<<dim3(maxNwave, 1, 3), 256, 0, stream>>>(hlP, offsP, csrP, att1P, b1P, RbP, N3);
    bn_stats_all_k<<<dim3(512, 3), 256, 0, stream>>>(RbCP, st1P, N3);
    bn_apply_all_k<<<dim3(maxNwave, 3), 256, 0, stream>>>(RbP, st1CP, bn_g, bn_b, N3);

    // ---- layer 2 (A = Rb bf16, in-place BN output) ----
    mfma_gemm_all_k<0><<<dim3(maxMtile, 4, 3), 256, 0, stream>>>(RbCP, Bt2P, CP, N3, 256);
    gat_gather_all_k<<<dim3(maxNwave, 1, 3), 256, 0, stream>>>(hlP, offsP, csrP, att2P, b2P, RbP, N3);
    bn_stats_all_k<<<dim3(512, 3), 256, 0, stream>>>(RbCP, st2P, N3);

    // ---- fused BN + lrelu + classifier ----
    bn_cls_all_k<<<dim3(maxNwave, 3), 256, 0, stream>>>(RbCP, st2CP, bn_g, bn_b, cW, cb, outP, N3);
}